// Round 14
// baseline (644.821 us; speedup 1.0000x reference)
//
#include <hip/hip_runtime.h>

typedef unsigned int uint;
typedef unsigned short ushort;

typedef __attribute__((ext_vector_type(8))) short sh8;
typedef __attribute__((ext_vector_type(4))) float f32x4;

__device__ __forceinline__ ushort f2b(float f) {
    uint x = __float_as_uint(f);
    x += 0x7fffu + ((x >> 16) & 1u);
    return (ushort)(x >> 16);
}
__device__ __forceinline__ float b2f(ushort u) {
    return __uint_as_float(((uint)u) << 16);
}
__device__ __forceinline__ uint pack2(float a, float b) {
    return (uint)f2b(a) | ((uint)f2b(b) << 16);
}
// RTNE pack of two f32 -> two bf16 in one instruction.
__device__ __forceinline__ uint cvt_pk_bf16(float lo, float hi) {
    uint r;
    asm("v_cvt_pk_bf16_f32 %0, %1, %2" : "=v"(r) : "v"(lo), "v"(hi));
    return r;
}
__device__ __forceinline__ float frcp(float x) { return __builtin_amdgcn_rcpf(x); }
__device__ __forceinline__ float sigmf(float x) { return frcp(1.0f + __expf(-x)); }
__device__ __forceinline__ float tanhf2(float y) {
    return fmaf(2.0f, frcp(1.0f + __expf(-2.0f * y)), -1.0f);
}

// ---------------------------------------------------------------------------
// Index-width detector for x (robustness; x believed int32).
// ---------------------------------------------------------------------------
__global__ __launch_bounds__(256) void k_detx(const uint* __restrict__ xw,
                                              int* __restrict__ flag) {
    __shared__ int sh[256];
    int t = threadIdx.x;
    int c = 0;
    for (int i = t; i < 2048; i += 256) c += (xw[2 * i + 1] == 0u) ? 1 : 0;
    sh[t] = c;
    __syncthreads();
    if (t == 0) {
        int s = 0;
        for (int i = 0; i < 256; i++) s += sh[i];
        flag[0] = (s >= 1843) ? 1 : 0;  // >=90% zeros -> int64
    }
}

// ---------------------------------------------------------------------------
// Embedding gather, fp32 -> bf16, index-width aware.
// ---------------------------------------------------------------------------
__global__ __launch_bounds__(256) void k_gather(const void* __restrict__ x,
                                                const float* __restrict__ embed,
                                                const int* __restrict__ flag,
                                                ushort* __restrict__ out) {
    int chunk = blockIdx.x * 256 + threadIdx.x;
    int row = chunk >> 5;
    int c = chunk & 31;
    int v;
    if (flag[0]) {
        v = (int)((const uint*)x)[2 * row];
    } else {
        v = ((const int*)x)[row];
    }
    v = min(max(v, 0), 49999);
    const float4* e = (const float4*)&embed[(size_t)v * 256 + (size_t)c * 8];
    float4 a = e[0], b = e[1];
    uint4 pv;
    pv.x = pack2(a.x, a.y);
    pv.y = pack2(a.z, a.w);
    pv.z = pack2(b.x, b.y);
    pv.w = pack2(b.z, b.w);
    *(uint4*)&out[(size_t)row * 256 + (size_t)c * 8] = pv;
}

// ---------------------------------------------------------------------------
// GEMM v2: C = A(bf16) * W^T(fp32 inline->bf16) + bias, optional GELU; bf16
// Cb and/or fp32 Cf outputs. NEW vs r12: K-tile 32 -> 64, realized as TWO
// independent 32-col panels (Al[2]/Bl[2]) that each keep the r11-verified
// layout, GLDS16 staging addressing (contiguous dest, 64B rows,
// conflict-free) and fragment reads. Only the barrier cadence changes:
// one __syncthreads pair per 64-K instead of per 32-K (16 -> 8 barriers at
// K=256), with 32 MFMA/wave per compute phase. LDS 32KB/block.
// ---------------------------------------------------------------------------
#define GLDS16(gsrc, ldst)                                                    \
    __builtin_amdgcn_global_load_lds(                                         \
        (const __attribute__((address_space(1))) uint*)(gsrc),                \
        (__attribute__((address_space(3))) uint*)(ldst), 16, 0, 0)

__global__ __launch_bounds__(256) void k_gemm_bt(const ushort* __restrict__ A,
                                                 const float* __restrict__ Wf,
                                                 const float* __restrict__ bias,
                                                 ushort* __restrict__ Cb,
                                                 float* __restrict__ Cf,
                                                 int M, int N, int K, int gelu) {
    __shared__ __align__(16) ushort Al[2][128 * 32];
    __shared__ __align__(16) ushort Bl[2][128 * 32];
    int tid = threadIdx.x;
    int bm = blockIdx.x, bn = blockIdx.y;
    int wid = tid >> 6, lane = tid & 63;
    int ln = lane & 15, kq = lane >> 4;
    int wm = (wid & 1) * 64, wn = (wid >> 1) * 64;
    int rowA0 = bm * 128, rowB0 = bn * 128;

    f32x4 acc[4][4];
#pragma unroll
    for (int i = 0; i < 4; i++)
#pragma unroll
        for (int j = 0; j < 4; j++) acc[i][j] = (f32x4){0.f, 0.f, 0.f, 0.f};

    int ra = tid >> 2, ca8 = (tid & 3) * 8;  // A-staging coords (16B/lane)

    for (int kt = 0; kt < K; kt += 64) {
        // A panels: async global->LDS, 2 x 16B per thread per panel.
#pragma unroll
        for (int ks = 0; ks < 2; ks++) {
            GLDS16(&A[(size_t)(rowA0 + ra) * K + kt + ks * 32 + ca8],
                   &Al[ks][tid * 8]);
            GLDS16(&A[(size_t)(rowA0 + 64 + ra) * K + kt + ks * 32 + ca8],
                   &Al[ks][2048 + tid * 8]);
        }
        // B panels: reg path with inline fp32->bf16.
#pragma unroll
        for (int ks = 0; ks < 2; ks++)
#pragma unroll
            for (int c = tid; c < 512; c += 256) {
                int r = c >> 2, c8 = (c & 3) * 8;
                int nb = rowB0 + r;
                uint4 bv = {0u, 0u, 0u, 0u};
                if (nb < N) {
                    const float4* wp =
                        (const float4*)&Wf[(size_t)nb * K + kt + ks * 32 + c8];
                    float4 w0 = wp[0], w1 = wp[1];
                    bv.x = pack2(w0.x, w0.y);
                    bv.y = pack2(w0.z, w0.w);
                    bv.z = pack2(w1.x, w1.y);
                    bv.w = pack2(w1.z, w1.w);
                }
                *(uint4*)&Bl[ks][r * 32 + c8] = bv;
            }
        __syncthreads();
#pragma unroll
        for (int ks = 0; ks < 2; ks++) {
            sh8 af[4], bfr[4];
#pragma unroll
            for (int i = 0; i < 4; i++)
                af[i] = *(const sh8*)&Al[ks][(wm + i * 16 + ln) * 32 + kq * 8];
#pragma unroll
            for (int j = 0; j < 4; j++)
                bfr[j] = *(const sh8*)&Bl[ks][(wn + j * 16 + ln) * 32 + kq * 8];
#pragma unroll
            for (int i = 0; i < 4; i++)
#pragma unroll
                for (int j = 0; j < 4; j++)
                    acc[i][j] = __builtin_amdgcn_mfma_f32_16x16x32_bf16(
                        af[i], bfr[j], acc[i][j], 0, 0, 0);
        }
        __syncthreads();
    }

#pragma unroll
    for (int i = 0; i < 4; i++)
#pragma unroll
        for (int j = 0; j < 4; j++) {
            int col = rowB0 + wn + j * 16 + ln;
            if (col >= N) continue;
            float bv = bias[col];
#pragma unroll
            for (int reg = 0; reg < 4; reg++) {
                int row = rowA0 + wm + i * 16 + kq * 4 + reg;
                float v = acc[i][j][reg] + bv;
                if (gelu) v = 0.5f * v * (1.0f + erff(v * 0.70710678118f));
                if (Cb) Cb[(size_t)row * N + col] = f2b(v);
                if (Cf) Cf[(size_t)row * N + col] = v;
            }
        }
}

// ---------------------------------------------------------------------------
// GRU recurrence v11 — EXACT r12-verified kernel (203 us/dispatch, absmax
// 0.00195). Structure: 32 blocks (4 batches x 1 dir), 512 threads, 1
// output/lane, 12 MFMA/wave, consecutive-replication A (row i = batch i>>2,
// LDS read (ln>>2)*144 => lane's batch in reg 0 of every accumulator, no
// selects), s_setprio around MFMA cluster, LDS [2][4][144] double-buffer,
// counted-vmcnt asm stream (4 loads + 1 store/step, waits 4,5,6,...,6,2).
// ---------------------------------------------------------------------------
struct PF {
    uint xr, xz, xn, rv;
};

#define GLOAD(dst, off, base, IMM)                                            \
    asm volatile("global_load_ushort %0, %1, %2 offset:" IMM                  \
                 : "=v"(dst)                                                  \
                 : "v"(off), "s"(base))

#define GSTORE(off, data, base)                                               \
    asm volatile("global_store_short %0, %1, %2" ::"v"(off), "v"(data),       \
                 "s"(base))

#define PREF(p)                                                               \
    {                                                                         \
        GLOAD(p.xr, xo_ld, xp, "0");                                          \
        GLOAD(p.xz, xo_ld, xp, "256");                                        \
        GLOAD(p.xn, xo_ld, xp, "512");                                        \
        GLOAD(p.rv, ho_ld, hb, "0");                                          \
        xo_ld += XS;                                                          \
        ho_ld += HS;                                                          \
    }

#define GSTEP(PAR, p, WN, DP)                                                 \
    {                                                                         \
        asm volatile("s_waitcnt vmcnt(" #WN ")");                             \
        __builtin_amdgcn_sched_barrier(0);                                    \
        float xr = __uint_as_float(p.xr << 16);                               \
        float xz = __uint_as_float(p.xz << 16);                               \
        float xn = __uint_as_float(p.xn << 16);                               \
        float rv = __uint_as_float(p.rv << 16);                               \
        if (DP) {                                                             \
            PREF(p)                                                           \
        }                                                                     \
        const ushort* hrd = lds + (PAR)*576 + (ln >> 2) * 144 + kq * 8;       \
        sh8 a0 = *(const sh8*)(hrd);                                          \
        sh8 a1 = *(const sh8*)(hrd + 32);                                     \
        sh8 a2 = *(const sh8*)(hrd + 64);                                     \
        sh8 a3 = *(const sh8*)(hrd + 96);                                     \
        f32x4 accr = (f32x4){0.f, 0.f, 0.f, 0.f};                             \
        f32x4 accz = accr, accn = accr;                                       \
        __builtin_amdgcn_s_setprio(1);                                        \
        accr = __builtin_amdgcn_mfma_f32_16x16x32_bf16(a0, bfrag[0][0], accr, 0, 0, 0); \
        accz = __builtin_amdgcn_mfma_f32_16x16x32_bf16(a0, bfrag[1][0], accz, 0, 0, 0); \
        accn = __builtin_amdgcn_mfma_f32_16x16x32_bf16(a0, bfrag[2][0], accn, 0, 0, 0); \
        accr = __builtin_amdgcn_mfma_f32_16x16x32_bf16(a1, bfrag[0][1], accr, 0, 0, 0); \
        accz = __builtin_amdgcn_mfma_f32_16x16x32_bf16(a1, bfrag[1][1], accz, 0, 0, 0); \
        accn = __builtin_amdgcn_mfma_f32_16x16x32_bf16(a1, bfrag[2][1], accn, 0, 0, 0); \
        accr = __builtin_amdgcn_mfma_f32_16x16x32_bf16(a2, bfrag[0][2], accr, 0, 0, 0); \
        accz = __builtin_amdgcn_mfma_f32_16x16x32_bf16(a2, bfrag[1][2], accz, 0, 0, 0); \
        accn = __builtin_amdgcn_mfma_f32_16x16x32_bf16(a2, bfrag[2][2], accn, 0, 0, 0); \
        accr = __builtin_amdgcn_mfma_f32_16x16x32_bf16(a3, bfrag[0][3], accr, 0, 0, 0); \
        accz = __builtin_amdgcn_mfma_f32_16x16x32_bf16(a3, bfrag[1][3], accz, 0, 0, 0); \
        accn = __builtin_amdgcn_mfma_f32_16x16x32_bf16(a3, bfrag[2][3], accn, 0, 0, 0); \
        __builtin_amdgcn_s_setprio(0);                                        \
        float rg = sigmf(xr + accr[0] + bh_r);                                \
        float zg = sigmf(xz + accz[0] + bh_z);                                \
        float ng = tanhf2(fmaf(rg, accn[0] + bh_n, xn));                      \
        float h = fmaf(zg, hstate - ng, ng);                                  \
        hstate = h;                                                           \
        float sv = h + rv;                                                    \
        uint pk = cvt_pk_bf16(h, sv);                                         \
        lds[(1 - (PAR)) * 576 + ob * 144 + jcol] = (ushort)pk;                \
        uint svb = pk >> 16;                                                  \
        GSTORE(ho_st, svb, hb);                                               \
        ho_st += HS;                                                          \
        asm volatile("s_waitcnt lgkmcnt(0)");                                 \
        __builtin_amdgcn_sched_barrier(0);                                    \
        __builtin_amdgcn_s_barrier();                                        \
        __builtin_amdgcn_sched_barrier(0);                                    \
    }

template <int DS>  // +1 forward, -1 backward
__device__ __forceinline__ void gru_impl(const ushort* __restrict__ xp,
                                         const float* __restrict__ Whh_l,
                                         const float* __restrict__ bhh_l,
                                         ushort* __restrict__ hb,
                                         int dir, int b_base, int t,
                                         ushort* lds) {
    constexpr int XS = DS * 1536;  // xp row stride per time step, bytes
    constexpr int HS = DS * 512;   // hb row stride per time step, bytes
    const int w = t >> 6, l = t & 63;
    const int ln = l & 15, kq = l >> 4;
    const int jcol = (w << 4) + ln;  // output col (and B-frag row)
    const int ob = kq;               // output batch index 0..3

    const float* Wd = Whh_l + (size_t)dir * 384 * 128;
    const float* bhh_d = bhh_l + dir * 384;

    // Whh B-fragments, bf16, resident in VGPRs.
    sh8 bfrag[3][4];
#pragma unroll
    for (int g = 0; g < 3; g++)
#pragma unroll
        for (int kt = 0; kt < 4; kt++) {
            const float4* wp =
                (const float4*)(Wd + (size_t)(g * 128 + jcol) * 128 + kt * 32 + kq * 8);
            float4 w0 = wp[0], w1 = wp[1];
            uint4 pv;
            pv.x = pack2(w0.x, w0.y);
            pv.y = pack2(w0.z, w0.w);
            pv.z = pack2(w1.x, w1.y);
            pv.w = pack2(w1.z, w1.w);
            bfrag[g][kt] = *(sh8*)&pv;
        }

    const float bh_r = bhh_d[jcol];
    const float bh_z = bhh_d[128 + jcol];
    const float bh_n = bhh_d[256 + jcol];
    asm volatile("" ::"v"(bh_r), "v"(bh_z), "v"(bh_n));

    // Running byte voffsets for THIS lane's single output (b_base+ob, jcol).
    const int t0 = (DS > 0) ? 0 : 511;
    int row0 = (b_base + ob) * 512 + t0;
    int xo_ld = row0 * 1536 + (dir * 384 + jcol) * 2;
    int ho_ld = row0 * 512 + (dir * 128 + jcol) * 2;
    int ho_st = ho_ld;

    float hstate = 0.f;

    // zero both h buffers (2 x 4 rows x 144)
    for (int i = t; i < 2 * 576; i += 512) lds[i] = 0;
    __syncthreads();  // full drain; vmcnt==0 from here

    PF pA, pB;
    PREF(pA)  // t0   (4 loads)
    PREF(pB)  // t0+1 (4 loads)

    GSTEP(0, pA, 4, 1)  // s = 0
    GSTEP(1, pB, 5, 1)  // s = 1
    for (int s = 2; s < 510; s += 2) {
        GSTEP(0, pA, 6, 1)
        GSTEP(1, pB, 6, 1)
    }
    GSTEP(0, pA, 6, 0)  // s = 510 (no prefetch)
    GSTEP(1, pB, 2, 0)  // s = 511
}

__global__ __launch_bounds__(512, 1) void k_gru(const ushort* __restrict__ xp,
                                                const float* __restrict__ Whh_l,
                                                const float* __restrict__ bhh_l,
                                                ushort* __restrict__ hb) {
    __shared__ __align__(16) ushort lds[2 * 576];
    const int dir = blockIdx.x & 1;
    const int b_base = (blockIdx.x >> 1) << 2;  // 4 batches per block
    if (dir == 0)
        gru_impl<1>(xp, Whh_l, bhh_l, hb, dir, b_base, threadIdx.x, lds);
    else
        gru_impl<-1>(xp, Whh_l, bhh_l, hb, dir, b_base, threadIdx.x, lds);
}

// ---------------------------------------------------------------------------
// Host launcher. fp32 inputs AND fp32 output; bf16 internally for MFMA.
// Scratch confined to 64 MiB:
//   [0, 48M)  xp (bf16 32768x768) — also hosts embA, then g (16 MiB each)
//   [48,64M)  hb (bf16 32768x256) — W1 out, GRU layers update in place
// ---------------------------------------------------------------------------
extern "C" void kernel_launch(void* const* d_in, const int* in_sizes, int n_in,
                              void* d_out, int out_size, void* d_ws, size_t ws_size,
                              hipStream_t stream) {
    const void* x = d_in[0];
    const float* embed = (const float*)d_in[1];
    const float* W1 = (const float*)d_in[2];
    const float* b1 = (const float*)d_in[3];
    const float* Wih = (const float*)d_in[4];  // [2][2][384][256]
    const float* Whh = (const float*)d_in[5];  // [2][2][384][128]
    const float* bih = (const float*)d_in[6];  // [2][2][384]
    const float* bhh = (const float*)d_in[7];  // [2][2][384]
    const float* W2 = (const float*)d_in[8];
    const float* b2 = (const float*)d_in[9];
    const float* W3 = (const float*)d_in[10];
    const float* b3 = (const float*)d_in[11];

    char* ws = (char*)d_ws;
    ushort* xp = (ushort*)ws;                         // [0, 48M)
    ushort* hb = (ushort*)(ws + 32768ull * 768 * 2);  // [48M, 64M)
    ushort* embA = xp;  // 16 MiB slot, dead after W1 GEMM
    ushort* g = xp;     // reused after last GRU
    int* xflag = (int*)hb;  // transient; dead after k_gather

    // detect x index width, then gather + W1: hb = bf16(embA @ W1^T + b1)
    k_detx<<<1, 256, 0, stream>>>((const uint*)x, xflag);
    k_gather<<<4096, 256, 0, stream>>>(x, embed, xflag, embA);
    k_gemm_bt<<<dim3(256, 2), 256, 0, stream>>>(embA, W1, b1, hb, (float*)0,
                                                32768, 256, 256, 0);

    // layer 0: xp = hb @ Wih[0]^T + bih[0]; GRU updates hb in place
    k_gemm_bt<<<dim3(256, 6), 256, 0, stream>>>(hb, Wih, bih, xp, (float*)0,
                                                32768, 768, 256, 0);
    k_gru<<<32, 512, 0, stream>>>(xp, Whh, bhh, hb);

    // layer 1
    k_gemm_bt<<<dim3(256, 6), 256, 0, stream>>>(hb, Wih + 196608, bih + 768,
                                                xp, (float*)0, 32768, 768, 256, 0);
    k_gru<<<32, 512, 0, stream>>>(xp, Whh + 98304, bhh + 768, hb);

    // head: g = bf16(GELU(hb @ W2^T + b2)); d_out = fp32(g @ W3^T + b3)
    k_gemm_bt<<<dim3(256, 2), 256, 0, stream>>>(hb, W2, b2, g, (float*)0,
                                                32768, 256, 256, 1);
    k_gemm_bt<<<dim3(256, 1), 256, 0, stream>>>(g, W3, b3, (ushort*)0,
                                                (float*)d_out, 32768, 50, 256, 0);
}

// Round 16
// 624.921 us; speedup vs baseline: 1.0318x; 1.0318x over previous
//
#include <hip/hip_runtime.h>

typedef unsigned int uint;
typedef unsigned short ushort;

typedef __attribute__((ext_vector_type(8))) short sh8;
typedef __attribute__((ext_vector_type(4))) float f32x4;

__device__ __forceinline__ ushort f2b(float f) {
    uint x = __float_as_uint(f);
    x += 0x7fffu + ((x >> 16) & 1u);
    return (ushort)(x >> 16);
}
__device__ __forceinline__ float b2f(ushort u) {
    return __uint_as_float(((uint)u) << 16);
}
__device__ __forceinline__ uint pack2(float a, float b) {
    return (uint)f2b(a) | ((uint)f2b(b) << 16);
}
// RTNE pack of two f32 -> two bf16 in one instruction.
__device__ __forceinline__ uint cvt_pk_bf16(float lo, float hi) {
    uint r;
    asm("v_cvt_pk_bf16_f32 %0, %1, %2" : "=v"(r) : "v"(lo), "v"(hi));
    return r;
}
__device__ __forceinline__ float frcp(float x) { return __builtin_amdgcn_rcpf(x); }
__device__ __forceinline__ float sigmf(float x) { return frcp(1.0f + __expf(-x)); }
__device__ __forceinline__ float tanhf2(float y) {
    return fmaf(2.0f, frcp(1.0f + __expf(-2.0f * y)), -1.0f);
}

// ---------------------------------------------------------------------------
// Index-width detector for x (robustness; x believed int32).
// ---------------------------------------------------------------------------
__global__ __launch_bounds__(256) void k_detx(const uint* __restrict__ xw,
                                              int* __restrict__ flag) {
    __shared__ int sh[256];
    int t = threadIdx.x;
    int c = 0;
    for (int i = t; i < 2048; i += 256) c += (xw[2 * i + 1] == 0u) ? 1 : 0;
    sh[t] = c;
    __syncthreads();
    if (t == 0) {
        int s = 0;
        for (int i = 0; i < 256; i++) s += sh[i];
        flag[0] = (s >= 1843) ? 1 : 0;  // >=90% zeros -> int64
    }
}

// ---------------------------------------------------------------------------
// Weight pre-conversion fp32 -> bf16 (RTNE, identical rounding to the old
// inline pack2 path -> bit-identical results). Runs ONCE. r15 BUG FIX: Wih
// is [2][2][384][256] = 393216 floats (NOT 786432 — r15 read 1.5MB OOB and
// crashed). Exact sizing: W1 65536 | Wih 393216 | W2 65536 = 524288 elems
// = 65536 threads x 8 = 256 blocks x 256 threads.
// Output layout in d_out scratch (weights dead before head GEMM overwrites):
//   [0,65536) W1b | [65536,458752) Wihb (both layers) | [458752,524288) W2b
// ---------------------------------------------------------------------------
__global__ __launch_bounds__(256) void k_convw(const float* __restrict__ W1,
                                               const float* __restrict__ Wih,
                                               const float* __restrict__ W2,
                                               ushort* __restrict__ out) {
    int i = blockIdx.x * 256 + threadIdx.x;  // [0, 65536)
    const float* src;
    size_t off;
    ushort* dst;
    if (i < 8192) {  // W1: 65536 floats
        src = W1;
        off = (size_t)i * 8;
        dst = out;
    } else if (i < 57344) {  // Wih: 393216 floats (both layers)
        src = Wih;
        off = (size_t)(i - 8192) * 8;
        dst = out + 65536;
    } else {  // W2: 65536 floats
        src = W2;
        off = (size_t)(i - 57344) * 8;
        dst = out + 65536 + 393216;
    }
    const float4* p = (const float4*)(src + off);
    float4 a = p[0], b = p[1];
    uint4 pv;
    pv.x = pack2(a.x, a.y);
    pv.y = pack2(a.z, a.w);
    pv.z = pack2(b.x, b.y);
    pv.w = pack2(b.z, b.w);
    *(uint4*)(dst + off) = pv;
}

// ---------------------------------------------------------------------------
// Embedding gather, fp32 -> bf16, index-width aware.
// ---------------------------------------------------------------------------
__global__ __launch_bounds__(256) void k_gather(const void* __restrict__ x,
                                                const float* __restrict__ embed,
                                                const int* __restrict__ flag,
                                                ushort* __restrict__ out) {
    int chunk = blockIdx.x * 256 + threadIdx.x;
    int row = chunk >> 5;
    int c = chunk & 31;
    int v;
    if (flag[0]) {
        v = (int)((const uint*)x)[2 * row];
    } else {
        v = ((const int*)x)[row];
    }
    v = min(max(v, 0), 49999);
    const float4* e = (const float4*)&embed[(size_t)v * 256 + (size_t)c * 8];
    float4 a = e[0], b = e[1];
    uint4 pv;
    pv.x = pack2(a.x, a.y);
    pv.y = pack2(a.z, a.w);
    pv.z = pack2(b.x, b.y);
    pv.w = pack2(b.z, b.w);
    *(uint4*)&out[(size_t)row * 256 + (size_t)c * 8] = pv;
}

#define GLDS16(gsrc, ldst)                                                    \
    __builtin_amdgcn_global_load_lds(                                         \
        (const __attribute__((address_space(1))) uint*)(gsrc),                \
        (__attribute__((address_space(3))) uint*)(ldst), 16, 0, 0)

// ---------------------------------------------------------------------------
// GEMM v3 (bf16 B): C = A(bf16) * Wb^T(bf16) + bias, optional GELU.
// Both A and B tiles staged via the r11-verified GLDS16 pattern (wave-
// uniform dest + lane*16, 64B rows, conflict-free). Requires N % 128 == 0
// and K % 64 == 0 (true for W1/Wih/W2). K-tile 64 = two 32-col panels.
// ---------------------------------------------------------------------------
__global__ __launch_bounds__(256) void k_gemm_bb(const ushort* __restrict__ A,
                                                 const ushort* __restrict__ Wb,
                                                 const float* __restrict__ bias,
                                                 ushort* __restrict__ Cb,
                                                 float* __restrict__ Cf,
                                                 int M, int N, int K, int gelu) {
    __shared__ __align__(16) ushort Al[2][128 * 32];
    __shared__ __align__(16) ushort Bl[2][128 * 32];
    int tid = threadIdx.x;
    int bm = blockIdx.x, bn = blockIdx.y;
    int wid = tid >> 6, lane = tid & 63;
    int ln = lane & 15, kq = lane >> 4;
    int wm = (wid & 1) * 64, wn = (wid >> 1) * 64;
    int rowA0 = bm * 128, rowB0 = bn * 128;

    f32x4 acc[4][4];
#pragma unroll
    for (int i = 0; i < 4; i++)
#pragma unroll
        for (int j = 0; j < 4; j++) acc[i][j] = (f32x4){0.f, 0.f, 0.f, 0.f};

    int ra = tid >> 2, ca8 = (tid & 3) * 8;  // staging coords (16B/lane)

    for (int kt = 0; kt < K; kt += 64) {
#pragma unroll
        for (int ks = 0; ks < 2; ks++) {
            GLDS16(&A[(size_t)(rowA0 + ra) * K + kt + ks * 32 + ca8],
                   &Al[ks][tid * 8]);
            GLDS16(&A[(size_t)(rowA0 + 64 + ra) * K + kt + ks * 32 + ca8],
                   &Al[ks][2048 + tid * 8]);
            GLDS16(&Wb[(size_t)(rowB0 + ra) * K + kt + ks * 32 + ca8],
                   &Bl[ks][tid * 8]);
            GLDS16(&Wb[(size_t)(rowB0 + 64 + ra) * K + kt + ks * 32 + ca8],
                   &Bl[ks][2048 + tid * 8]);
        }
        __syncthreads();
#pragma unroll
        for (int ks = 0; ks < 2; ks++) {
            sh8 af[4], bfr[4];
#pragma unroll
            for (int i = 0; i < 4; i++)
                af[i] = *(const sh8*)&Al[ks][(wm + i * 16 + ln) * 32 + kq * 8];
#pragma unroll
            for (int j = 0; j < 4; j++)
                bfr[j] = *(const sh8*)&Bl[ks][(wn + j * 16 + ln) * 32 + kq * 8];
#pragma unroll
            for (int i = 0; i < 4; i++)
#pragma unroll
                for (int j = 0; j < 4; j++)
                    acc[i][j] = __builtin_amdgcn_mfma_f32_16x16x32_bf16(
                        af[i], bfr[j], acc[i][j], 0, 0, 0);
        }
        __syncthreads();
    }

#pragma unroll
    for (int i = 0; i < 4; i++)
#pragma unroll
        for (int j = 0; j < 4; j++) {
            int col = rowB0 + wn + j * 16 + ln;
            float bv = bias[col];
#pragma unroll
            for (int reg = 0; reg < 4; reg++) {
                int row = rowA0 + wm + i * 16 + kq * 4 + reg;
                float v = acc[i][j][reg] + bv;
                if (gelu) v = 0.5f * v * (1.0f + erff(v * 0.70710678118f));
                if (Cb) Cb[(size_t)row * N + col] = f2b(v);
                if (Cf) Cf[(size_t)row * N + col] = v;
            }
        }
}

// ---------------------------------------------------------------------------
// GEMM v2 (fp32 W inline-convert; r14-verified) — kept for the W3 head
// (N=50, not a multiple of 128; needs the nb<N staging guard).
// ---------------------------------------------------------------------------
__global__ __launch_bounds__(256) void k_gemm_bt(const ushort* __restrict__ A,
                                                 const float* __restrict__ Wf,
                                                 const float* __restrict__ bias,
                                                 ushort* __restrict__ Cb,
                                                 float* __restrict__ Cf,
                                                 int M, int N, int K, int gelu) {
    __shared__ __align__(16) ushort Al[2][128 * 32];
    __shared__ __align__(16) ushort Bl[2][128 * 32];
    int tid = threadIdx.x;
    int bm = blockIdx.x, bn = blockIdx.y;
    int wid = tid >> 6, lane = tid & 63;
    int ln = lane & 15, kq = lane >> 4;
    int wm = (wid & 1) * 64, wn = (wid >> 1) * 64;
    int rowA0 = bm * 128, rowB0 = bn * 128;

    f32x4 acc[4][4];
#pragma unroll
    for (int i = 0; i < 4; i++)
#pragma unroll
        for (int j = 0; j < 4; j++) acc[i][j] = (f32x4){0.f, 0.f, 0.f, 0.f};

    int ra = tid >> 2, ca8 = (tid & 3) * 8;

    for (int kt = 0; kt < K; kt += 64) {
#pragma unroll
        for (int ks = 0; ks < 2; ks++) {
            GLDS16(&A[(size_t)(rowA0 + ra) * K + kt + ks * 32 + ca8],
                   &Al[ks][tid * 8]);
            GLDS16(&A[(size_t)(rowA0 + 64 + ra) * K + kt + ks * 32 + ca8],
                   &Al[ks][2048 + tid * 8]);
        }
#pragma unroll
        for (int ks = 0; ks < 2; ks++)
#pragma unroll
            for (int c = tid; c < 512; c += 256) {
                int r = c >> 2, c8 = (c & 3) * 8;
                int nb = rowB0 + r;
                uint4 bv = {0u, 0u, 0u, 0u};
                if (nb < N) {
                    const float4* wp =
                        (const float4*)&Wf[(size_t)nb * K + kt + ks * 32 + c8];
                    float4 w0 = wp[0], w1 = wp[1];
                    bv.x = pack2(w0.x, w0.y);
                    bv.y = pack2(w0.z, w0.w);
                    bv.z = pack2(w1.x, w1.y);
                    bv.w = pack2(w1.z, w1.w);
                }
                *(uint4*)&Bl[ks][r * 32 + c8] = bv;
            }
        __syncthreads();
#pragma unroll
        for (int ks = 0; ks < 2; ks++) {
            sh8 af[4], bfr[4];
#pragma unroll
            for (int i = 0; i < 4; i++)
                af[i] = *(const sh8*)&Al[ks][(wm + i * 16 + ln) * 32 + kq * 8];
#pragma unroll
            for (int j = 0; j < 4; j++)
                bfr[j] = *(const sh8*)&Bl[ks][(wn + j * 16 + ln) * 32 + kq * 8];
#pragma unroll
            for (int i = 0; i < 4; i++)
#pragma unroll
                for (int j = 0; j < 4; j++)
                    acc[i][j] = __builtin_amdgcn_mfma_f32_16x16x32_bf16(
                        af[i], bfr[j], acc[i][j], 0, 0, 0);
        }
        __syncthreads();
    }

#pragma unroll
    for (int i = 0; i < 4; i++)
#pragma unroll
        for (int j = 0; j < 4; j++) {
            int col = rowB0 + wn + j * 16 + ln;
            if (col >= N) continue;
            float bv = bias[col];
#pragma unroll
            for (int reg = 0; reg < 4; reg++) {
                int row = rowA0 + wm + i * 16 + kq * 4 + reg;
                float v = acc[i][j][reg] + bv;
                if (gelu) v = 0.5f * v * (1.0f + erff(v * 0.70710678118f));
                if (Cb) Cb[(size_t)row * N + col] = f2b(v);
                if (Cf) Cf[(size_t)row * N + col] = v;
            }
        }
}

// ---------------------------------------------------------------------------
// GRU recurrence v11 — EXACT r12/r14-verified kernel (202 us/dispatch,
// absmax 0.00195). 32 blocks (4 batches x 1 dir), 512 threads, 1
// output/lane, 12 MFMA/wave, consecutive-replication A (row i = batch i>>2,
// LDS read (ln>>2)*144 => lane's batch in reg 0 of every accumulator, no
// selects), s_setprio around MFMA cluster, LDS [2][4][144] double-buffer,
// counted-vmcnt asm stream (4 loads + 1 store/step, waits 4,5,6,...,6,2).
// ---------------------------------------------------------------------------
struct PF {
    uint xr, xz, xn, rv;
};

#define GLOAD(dst, off, base, IMM)                                            \
    asm volatile("global_load_ushort %0, %1, %2 offset:" IMM                  \
                 : "=v"(dst)                                                  \
                 : "v"(off), "s"(base))

#define GSTORE(off, data, base)                                               \
    asm volatile("global_store_short %0, %1, %2" ::"v"(off), "v"(data),       \
                 "s"(base))

#define PREF(p)                                                               \
    {                                                                         \
        GLOAD(p.xr, xo_ld, xp, "0");                                          \
        GLOAD(p.xz, xo_ld, xp, "256");                                        \
        GLOAD(p.xn, xo_ld, xp, "512");                                        \
        GLOAD(p.rv, ho_ld, hb, "0");                                          \
        xo_ld += XS;                                                          \
        ho_ld += HS;                                                          \
    }

#define GSTEP(PAR, p, WN, DP)                                                 \
    {                                                                         \
        asm volatile("s_waitcnt vmcnt(" #WN ")");                             \
        __builtin_amdgcn_sched_barrier(0);                                    \
        float xr = __uint_as_float(p.xr << 16);                               \
        float xz = __uint_as_float(p.xz << 16);                               \
        float xn = __uint_as_float(p.xn << 16);                               \
        float rv = __uint_as_float(p.rv << 16);                               \
        if (DP) {                                                             \
            PREF(p)                                                           \
        }                                                                     \
        const ushort* hrd = lds + (PAR)*576 + (ln >> 2) * 144 + kq * 8;       \
        sh8 a0 = *(const sh8*)(hrd);                                          \
        sh8 a1 = *(const sh8*)(hrd + 32);                                     \
        sh8 a2 = *(const sh8*)(hrd + 64);                                     \
        sh8 a3 = *(const sh8*)(hrd + 96);                                     \
        f32x4 accr = (f32x4){0.f, 0.f, 0.f, 0.f};                             \
        f32x4 accz = accr, accn = accr;                                       \
        __builtin_amdgcn_s_setprio(1);                                        \
        accr = __builtin_amdgcn_mfma_f32_16x16x32_bf16(a0, bfrag[0][0], accr, 0, 0, 0); \
        accz = __builtin_amdgcn_mfma_f32_16x16x32_bf16(a0, bfrag[1][0], accz, 0, 0, 0); \
        accn = __builtin_amdgcn_mfma_f32_16x16x32_bf16(a0, bfrag[2][0], accn, 0, 0, 0); \
        accr = __builtin_amdgcn_mfma_f32_16x16x32_bf16(a1, bfrag[0][1], accr, 0, 0, 0); \
        accz = __builtin_amdgcn_mfma_f32_16x16x32_bf16(a1, bfrag[1][1], accz, 0, 0, 0); \
        accn = __builtin_amdgcn_mfma_f32_16x16x32_bf16(a1, bfrag[2][1], accn, 0, 0, 0); \
        accr = __builtin_amdgcn_mfma_f32_16x16x32_bf16(a2, bfrag[0][2], accr, 0, 0, 0); \
        accz = __builtin_amdgcn_mfma_f32_16x16x32_bf16(a2, bfrag[1][2], accz, 0, 0, 0); \
        accn = __builtin_amdgcn_mfma_f32_16x16x32_bf16(a2, bfrag[2][2], accn, 0, 0, 0); \
        accr = __builtin_amdgcn_mfma_f32_16x16x32_bf16(a3, bfrag[0][3], accr, 0, 0, 0); \
        accz = __builtin_amdgcn_mfma_f32_16x16x32_bf16(a3, bfrag[1][3], accz, 0, 0, 0); \
        accn = __builtin_amdgcn_mfma_f32_16x16x32_bf16(a3, bfrag[2][3], accn, 0, 0, 0); \
        __builtin_amdgcn_s_setprio(0);                                        \
        float rg = sigmf(xr + accr[0] + bh_r);                                \
        float zg = sigmf(xz + accz[0] + bh_z);                                \
        float ng = tanhf2(fmaf(rg, accn[0] + bh_n, xn));                      \
        float h = fmaf(zg, hstate - ng, ng);                                  \
        hstate = h;                                                           \
        float sv = h + rv;                                                    \
        uint pk = cvt_pk_bf16(h, sv);                                         \
        lds[(1 - (PAR)) * 576 + ob * 144 + jcol] = (ushort)pk;                \
        uint svb = pk >> 16;                                                  \
        GSTORE(ho_st, svb, hb);                                               \
        ho_st += HS;                                                          \
        asm volatile("s_waitcnt lgkmcnt(0)");                                 \
        __builtin_amdgcn_sched_barrier(0);                                    \
        __builtin_amdgcn_s_barrier();                                         \
        __builtin_amdgcn_sched_barrier(0);                                    \
    }

template <int DS>  // +1 forward, -1 backward
__device__ __forceinline__ void gru_impl(const ushort* __restrict__ xp,
                                         const float* __restrict__ Whh_l,
                                         const float* __restrict__ bhh_l,
                                         ushort* __restrict__ hb,
                                         int dir, int b_base, int t,
                                         ushort* lds) {
    constexpr int XS = DS * 1536;  // xp row stride per time step, bytes
    constexpr int HS = DS * 512;   // hb row stride per time step, bytes
    const int w = t >> 6, l = t & 63;
    const int ln = l & 15, kq = l >> 4;
    const int jcol = (w << 4) + ln;  // output col (and B-frag row)
    const int ob = kq;               // output batch index 0..3

    const float* Wd = Whh_l + (size_t)dir * 384 * 128;
    const float* bhh_d = bhh_l + dir * 384;

    // Whh B-fragments, bf16, resident in VGPRs.
    sh8 bfrag[3][4];
#pragma unroll
    for (int g = 0; g < 3; g++)
#pragma unroll
        for (int kt = 0; kt < 4; kt++) {
            const float4* wp =
                (const float4*)(Wd + (size_t)(g * 128 + jcol) * 128 + kt * 32 + kq * 8);
            float4 w0 = wp[0], w1 = wp[1];
            uint4 pv;
            pv.x = pack2(w0.x, w0.y);
            pv.y = pack2(w0.z, w0.w);
            pv.z = pack2(w1.x, w1.y);
            pv.w = pack2(w1.z, w1.w);
            bfrag[g][kt] = *(sh8*)&pv;
        }

    const float bh_r = bhh_d[jcol];
    const float bh_z = bhh_d[128 + jcol];
    const float bh_n = bhh_d[256 + jcol];
    asm volatile("" ::"v"(bh_r), "v"(bh_z), "v"(bh_n));

    // Running byte voffsets for THIS lane's single output (b_base+ob, jcol).
    const int t0 = (DS > 0) ? 0 : 511;
    int row0 = (b_base + ob) * 512 + t0;
    int xo_ld = row0 * 1536 + (dir * 384 + jcol) * 2;
    int ho_ld = row0 * 512 + (dir * 128 + jcol) * 2;
    int ho_st = ho_ld;

    float hstate = 0.f;

    // zero both h buffers (2 x 4 rows x 144)
    for (int i = t; i < 2 * 576; i += 512) lds[i] = 0;
    __syncthreads();  // full drain; vmcnt==0 from here

    PF pA, pB;
    PREF(pA)  // t0   (4 loads)
    PREF(pB)  // t0+1 (4 loads)

    GSTEP(0, pA, 4, 1)  // s = 0
    GSTEP(1, pB, 5, 1)  // s = 1
    for (int s = 2; s < 510; s += 2) {
        GSTEP(0, pA, 6, 1)
        GSTEP(1, pB, 6, 1)
    }
    GSTEP(0, pA, 6, 0)  // s = 510 (no prefetch)
    GSTEP(1, pB, 2, 0)  // s = 511
}

__global__ __launch_bounds__(512, 1) void k_gru(const ushort* __restrict__ xp,
                                                const float* __restrict__ Whh_l,
                                                const float* __restrict__ bhh_l,
                                                ushort* __restrict__ hb) {
    __shared__ __align__(16) ushort lds[2 * 576];
    const int dir = blockIdx.x & 1;
    const int b_base = (blockIdx.x >> 1) << 2;  // 4 batches per block
    if (dir == 0)
        gru_impl<1>(xp, Whh_l, bhh_l, hb, dir, b_base, threadIdx.x, lds);
    else
        gru_impl<-1>(xp, Whh_l, bhh_l, hb, dir, b_base, threadIdx.x, lds);
}

// ---------------------------------------------------------------------------
// Host launcher. fp32 inputs AND fp32 output; bf16 internally for MFMA.
// Scratch: 64 MiB workspace (xp 48M | hb 16M) + d_out (6.5 MB) hosting the
// pre-converted bf16 weights (1.05 MB) until the head GEMM overwrites it.
// ---------------------------------------------------------------------------
extern "C" void kernel_launch(void* const* d_in, const int* in_sizes, int n_in,
                              void* d_out, int out_size, void* d_ws, size_t ws_size,
                              hipStream_t stream) {
    const void* x = d_in[0];
    const float* embed = (const float*)d_in[1];
    const float* W1 = (const float*)d_in[2];
    const float* b1 = (const float*)d_in[3];
    const float* Wih = (const float*)d_in[4];  // [2][2][384][256] = 393216 floats
    const float* Whh = (const float*)d_in[5];  // [2][2][384][128]
    const float* bih = (const float*)d_in[6];  // [2][2][384]
    const float* bhh = (const float*)d_in[7];  // [2][2][384]
    const float* W2 = (const float*)d_in[8];
    const float* b2 = (const float*)d_in[9];
    const float* W3 = (const float*)d_in[10];
    const float* b3 = (const float*)d_in[11];

    char* ws = (char*)d_ws;
    ushort* xp = (ushort*)ws;                         // [0, 48M)
    ushort* hb = (ushort*)(ws + 32768ull * 768 * 2);  // [48M, 64M)
    ushort* embA = xp;  // 16 MiB slot, dead after W1 GEMM
    ushort* g = xp;     // reused after last GRU
    int* xflag = (int*)hb;  // transient; dead after k_gather

    // bf16 weights in d_out scratch (dead before the head GEMM writes d_out)
    ushort* wb = (ushort*)d_out;
    ushort* W1b = wb;                    // 65536 elems
    ushort* Wihb = wb + 65536;           // 393216 elems (both layers)
    ushort* W2b = wb + 65536 + 393216;   // 65536 elems

    // detect x index width; convert weights; gather + W1
    k_detx<<<1, 256, 0, stream>>>((const uint*)x, xflag);
    k_convw<<<256, 256, 0, stream>>>(W1, Wih, W2, wb);
    k_gather<<<4096, 256, 0, stream>>>(x, embed, xflag, embA);
    k_gemm_bb<<<dim3(256, 2), 256, 0, stream>>>(embA, W1b, b1, hb, (float*)0,
                                                32768, 256, 256, 0);

    // layer 0: xp = hb @ Wih[0]^T + bih[0]; GRU updates hb in place
    k_gemm_bb<<<dim3(256, 6), 256, 0, stream>>>(hb, Wihb, bih, xp, (float*)0,
                                                32768, 768, 256, 0);
    k_gru<<<32, 512, 0, stream>>>(xp, Whh, bhh, hb);

    // layer 1
    k_gemm_bb<<<dim3(256, 6), 256, 0, stream>>>(hb, Wihb + 196608, bih + 768,
                                                xp, (float*)0, 32768, 768, 256, 0);
    k_gru<<<32, 512, 0, stream>>>(xp, Whh + 98304, bhh + 768, hb);

    // head: g = bf16(GELU(hb @ W2^T + b2)); d_out = fp32(g @ W3^T + b3)
    k_gemm_bb<<<dim3(256, 2), 256, 0, stream>>>(hb, W2b, b2, g, (float*)0,
                                                32768, 256, 256, 1);
    k_gemm_bt<<<dim3(256, 1), 256, 0, stream>>>(g, W3, b3, (ushort*)0,
                                                (float*)d_out, 32768, 50, 256, 0);
}